// Round 8
// baseline (275.946 us; speedup 1.0000x reference)
//
#include <hip/hip_runtime.h>
#include <stdint.h>

#define B_ 8
#define N_ 2048
#define D_ 768

typedef unsigned short u16;
typedef unsigned int u32;
typedef __attribute__((ext_vector_type(8))) short bf16x8;
typedef __attribute__((ext_vector_type(8))) unsigned short u16x8;
typedef __attribute__((ext_vector_type(4))) float f32x4;

static constexpr float INV_SCALE = 0.10825317547305482f; // 3/sqrt(768)

__device__ __forceinline__ u16 f2bf(float f) {
  union { float f; unsigned u; } v; v.f = f;
  return (u16)((v.u + 0x7FFFu + ((v.u >> 16) & 1u)) >> 16);
}
__device__ __forceinline__ float bf2f(u16 h) {
  union { unsigned u; float f; } v; v.u = ((unsigned)h) << 16;
  return v.f;
}
__device__ __forceinline__ f32x4 mfma16(bf16x8 a, bf16x8 b, f32x4 c) {
  return __builtin_amdgcn_mfma_f32_16x16x32_bf16(a, b, c, 0, 0, 0);
}
__device__ __forceinline__ void gl_lds16(const u16* g, u16* l) {
  __builtin_amdgcn_global_load_lds(
      (const __attribute__((address_space(1))) u32*)g,
      (__attribute__((address_space(3))) u32*)l, 16, 0, 0);
}

// ---------------- K0: cast x, Wq, Wk, Wv to bf16 ----------------
__global__ __launch_bounds__(256) void cast_kernel(
    const float* __restrict__ x, const float* __restrict__ wq,
    const float* __restrict__ wk, const float* __restrict__ wv,
    u16* __restrict__ xb, u16* __restrict__ wqb,
    u16* __restrict__ wkb, u16* __restrict__ wvb) {
  const long NX = (long)B_ * N_ * D_;
  const long NW = (long)D_ * D_;
  long i = ((long)blockIdx.x * 256 + threadIdx.x) * 8;
  const float* src; u16* dst; long off;
  if (i < NX) { src = x; dst = xb; off = i; }
  else {
    long j = i - NX;
    int seg = (int)(j / NW);
    off = j - (long)seg * NW;
    src = seg == 0 ? wq : (seg == 1 ? wk : wv);
    dst = seg == 0 ? wqb : (seg == 1 ? wkb : wvb);
  }
  float4 a = *(const float4*)(src + off);
  float4 b = *(const float4*)(src + off + 4);
  u16x8 o;
  o[0]=f2bf(a.x); o[1]=f2bf(a.y); o[2]=f2bf(a.z); o[3]=f2bf(a.w);
  o[4]=f2bf(b.x); o[5]=f2bf(b.y); o[6]=f2bf(b.z); o[7]=f2bf(b.w);
  *(u16x8*)(dst + off) = o;
}

// ==== 256x256 BK=64 GEMM core: 8 waves (2M x 4N), wave tile 128x64 ====
// 8-phase-class schedule (m201 family):
//  - per K-tile: 4 quadrant phases, each {12 ds_read_b128; barrier;
//    setprio(1) 16 MFMA setprio(0); barrier}
//  - staging: ALL 8 gl_lds for tile t+1 issued at tile t phase 0, then
//    counted vmcnt(8) (never 0 mid-loop) -> issue->use distance = 4 phases.
//  - LDS: [256 rows][64 k] per operand, double-buffered = 128 KB.
//  - swizzle both sides (rule 21): phys 16B-slot = logical ^ (row&7).
// WAR-safe: a buffer's reads retire before their phase-end barrier (operands
// consumed by MFMA pre-barrier); the overwriting stage is >=5 phases later.
template<int NT>
__device__ __forceinline__ void gemm256(
    const u16* __restrict__ Ag, long lda,
    const u16* __restrict__ Bg, long ldb,
    f32x4 (&acc)[8][4]) {
  __shared__ u16 Ab[2][16384];
  __shared__ u16 Bb[2][16384];
  const int t_ = threadIdx.x, l = t_ & 63, w = t_ >> 6;
  const int lr = l & 15, kq = l >> 4;          // kq in [0,4)
  const int wm = w >> 2, wn = w & 3;
  const int arow = wm * 128, brow = wn * 64;

  // staging decode: lane writes LDS byte d = j*8192 + w*1024 + l*16
  //   row = j*64 + w*8 + (l>>3); phys slot = l&7; logical slot = (l&7)^(l>>3)
  const int s_rowl = l >> 3;                   // lane row part + row&7
  const int s_sl = (l & 7) ^ (l >> 3);         // pre-swizzled source slot
  auto STAGE = [&](u16* As, u16* Bs, int kt) {
    #pragma unroll
    for (int j = 0; j < 4; ++j) {
      const int dofs = (j * 8192 + w * 1024) >> 1;       // u16 units, wave-uniform
      const int row = j * 64 + w * 8 + s_rowl;
      gl_lds16(Ag + (long)row * lda + kt * 64 + s_sl * 8, As + dofs);
      gl_lds16(Bg + (long)row * ldb + kt * 64 + s_sl * 8, Bs + dofs);
    }
  };

  // quadrant phase: QM in {0,1} (A row half), QN in {0,1} (B col half)
#define PHQ(AS, BS, QM, QN)                                              \
  {                                                                      \
    bf16x8 af[4][2], bf[2][2];                                           \
    _Pragma("unroll")                                                    \
    for (int mf = 0; mf < 4; ++mf) {                                     \
      const int row = arow + (QM * 4 + mf) * 16 + lr;                    \
      _Pragma("unroll")                                                  \
      for (int ks = 0; ks < 2; ++ks)                                     \
        af[mf][ks] = *(const bf16x8*)(AS + row * 64 +                    \
                        (((4 * ks + kq) ^ (lr & 7)) * 8));               \
    }                                                                    \
    _Pragma("unroll")                                                    \
    for (int nf = 0; nf < 2; ++nf) {                                     \
      const int row = brow + (QN * 2 + nf) * 16 + lr;                    \
      _Pragma("unroll")                                                  \
      for (int ks = 0; ks < 2; ++ks)                                     \
        bf[nf][ks] = *(const bf16x8*)(BS + row * 64 +                    \
                        (((4 * ks + kq) ^ (lr & 7)) * 8));               \
    }                                                                    \
    __builtin_amdgcn_s_barrier();                                        \
    __builtin_amdgcn_s_setprio(1);                                       \
    _Pragma("unroll")                                                    \
    for (int mf = 0; mf < 4; ++mf)                                       \
      _Pragma("unroll")                                                  \
      for (int nf = 0; nf < 2; ++nf)                                     \
        acc[QM * 4 + mf][QN * 2 + nf] =                                  \
            mfma16(af[mf][0], bf[nf][0], acc[QM * 4 + mf][QN * 2 + nf]); \
    _Pragma("unroll")                                                    \
    for (int mf = 0; mf < 4; ++mf)                                       \
      _Pragma("unroll")                                                  \
      for (int nf = 0; nf < 2; ++nf)                                     \
        acc[QM * 4 + mf][QN * 2 + nf] =                                  \
            mfma16(af[mf][1], bf[nf][1], acc[QM * 4 + mf][QN * 2 + nf]); \
    __builtin_amdgcn_s_setprio(0);                                       \
    asm volatile("" ::: "memory");                                       \
    __builtin_amdgcn_s_barrier();                                        \
  }

#define TILE(AC, BC, AN, BN2, kt, DOST)                                  \
  {                                                                      \
    if (DOST) {                                                          \
      STAGE(AN, BN2, (kt) + 1);                                          \
      asm volatile("s_waitcnt vmcnt(8)" ::: "memory");                   \
    } else {                                                             \
      asm volatile("s_waitcnt vmcnt(0)" ::: "memory");                   \
    }                                                                    \
    __builtin_amdgcn_s_barrier();                                        \
    PHQ(AC, BC, 0, 0)                                                    \
    PHQ(AC, BC, 0, 1)                                                    \
    PHQ(AC, BC, 1, 0)                                                    \
    PHQ(AC, BC, 1, 1)                                                    \
  }

  STAGE(Ab[0], Bb[0], 0);
  for (int t2 = 0; t2 < NT; t2 += 2) {
    TILE(Ab[0], Bb[0], Ab[1], Bb[1], t2, true)
    TILE(Ab[1], Bb[1], Ab[0], Bb[0], t2 + 1, (t2 + 2 < NT))
  }
#undef TILE
#undef PHQ
}

// ---------------- K1: Q/K/V = x @ W^T + b (Q scaled) ----------------
// grid 576 = 64 rt x 3 ct x 3 mat; XCD = rt-band (8 rt x 256 rows = 3 MB).
__global__ __launch_bounds__(512, 2) void qkv_gemm(
    const u16* __restrict__ xb,
    const u16* __restrict__ wq, const u16* __restrict__ wk, const u16* __restrict__ wv,
    const float* __restrict__ bq, const float* __restrict__ bk, const float* __restrict__ bv,
    u16* __restrict__ Qs, u16* __restrict__ Kb, u16* __restrict__ Vb) {
  const int lin = blockIdx.x;
  const int xcd = lin & 7, inner = lin >> 3;          // inner: 0..71
  const int rt = xcd * 8 + (inner & 7);
  const int rest = inner >> 3;                        // 0..8
  const int ct = rest % 3, mat = rest / 3;
  const u16* W = mat == 0 ? wq : (mat == 1 ? wk : wv);
  const float* bias = mat == 0 ? bq : (mat == 1 ? bk : bv);
  u16* out = mat == 0 ? Qs : (mat == 1 ? Kb : Vb);
  const float scl = mat == 0 ? INV_SCALE : 1.0f;
  const int rbase = rt * 256, cbase = ct * 256;

  f32x4 acc[8][4] = {};
  gemm256<D_ / 64>(xb + (long)rbase * D_, D_, W + (long)cbase * D_, D_, acc);

  const int l = threadIdx.x & 63, w = threadIdx.x >> 6;
  const int lr = l & 15, orow = (l >> 4) * 4;
  const int wm = w >> 2, wn = w & 3;
  #pragma unroll
  for (int mf = 0; mf < 8; ++mf)
    #pragma unroll
    for (int nf = 0; nf < 4; ++nf) {
      int col = cbase + wn * 64 + nf * 16 + lr;
      float bc = bias[col];
      #pragma unroll
      for (int r = 0; r < 4; ++r) {
        int row = rbase + wm * 128 + mf * 16 + orow + r;
        out[(long)row * D_ + col] = f2bf((acc[mf][nf][r] + bc) * scl);
      }
    }
}

// ---------------- K2: P = exp(Q.K^T), den partials ----------------
// grid 512 = 8 kblk x 8 qblk x 8 b; XCD = one b.
__global__ __launch_bounds__(512, 2) void qk_exp(
    const u16* __restrict__ Qs, const u16* __restrict__ Kb,
    u16* __restrict__ P, float* __restrict__ denpart) {
  const int lin = blockIdx.x;
  const int b = lin & 7, inner = lin >> 3;            // inner: 0..63
  const int kblk = inner & 7, qblk = inner >> 3;

  f32x4 acc[8][4] = {};
  gemm256<D_ / 64>(Qs + ((long)b * N_ + qblk * 256) * D_, D_,
                   Kb + ((long)b * N_ + kblk * 256) * D_, D_, acc);

  const int tt = threadIdx.x, l = tt & 63, w = tt >> 6;
  const int lr = l & 15, orow = (l >> 4) * 4;
  const int wm = w >> 2, wn = w & 3;
  float csum[4] = {0.f, 0.f, 0.f, 0.f};
  #pragma unroll
  for (int mf = 0; mf < 8; ++mf)
    #pragma unroll
    for (int nf = 0; nf < 4; ++nf) {
      long kk = kblk * 256 + wn * 64 + nf * 16 + lr;
      #pragma unroll
      for (int r = 0; r < 4; ++r) {
        long q = qblk * 256 + wm * 128 + mf * 16 + orow + r;
        float e = __expf(acc[mf][nf][r]);
        u16 pe = f2bf(e);
        P[((long)b * N_ + q) * N_ + kk] = pe;
        csum[nf] += bf2f(pe);
      }
    }
  // reduce over orow lane-groups -> column sums for this wave's 128 q rows
  #pragma unroll
  for (int nf = 0; nf < 4; ++nf) {
    csum[nf] += __shfl_xor(csum[nf], 16);
    csum[nf] += __shfl_xor(csum[nf], 32);
  }
  if (l < 16) {
    #pragma unroll
    for (int nf = 0; nf < 4; ++nf)
      denpart[((long)(qblk * 2 + wm) * B_ + b) * N_ +
              kblk * 256 + wn * 64 + nf * 16 + l] = csum[nf];
  }
}

// ---------------- K3: VsT[b][d][k] = V[b][k][d] / den[b][k] ----------------
__global__ __launch_bounds__(256) void scale_transpose(
    const u16* __restrict__ Vb, const float* __restrict__ denpart,
    u16* __restrict__ VsT) {
  const int b = blockIdx.z, k0 = blockIdx.y * 64, d0 = blockIdx.x * 64;
  __shared__ float tile[64][65];
  __shared__ float invden[64];
  const int t = threadIdx.x;
  if (t < 64) {
    float s = 0.f;
    for (int qs = 0; qs < 16; ++qs)
      s += denpart[((long)qs * B_ + b) * N_ + k0 + t];
    invden[t] = 1.0f / s;
  }
  __syncthreads();
  for (int idx = t; idx < 4096; idx += 256) {
    int kl = idx >> 6, dl = idx & 63;
    float v = bf2f(Vb[((long)b * N_ + k0 + kl) * D_ + d0 + dl]) * invden[kl];
    tile[dl][kl] = v;
  }
  __syncthreads();
  for (int idx = t; idx < 4096; idx += 256) {
    int dl = idx >> 6, kl = idx & 63;
    VsT[((long)b * D_ + d0 + dl) * N_ + k0 + kl] = f2bf(tile[dl][kl]);
  }
}

// ---------------- K4: out = P @ Vs + xb (bf16 residual) ----------------
// grid 192 = 8 qt x 3 dt x 8 b; XCD = one b (24 blocks): VsT_b L2-hot.
__global__ __launch_bounds__(512, 2) void pv_gemm(
    const u16* __restrict__ P, const u16* __restrict__ VsT,
    const u16* __restrict__ xb, float* __restrict__ out) {
  const int lin = blockIdx.x;
  const int b = lin & 7, inner = lin >> 3;            // inner: 0..23
  const int qt = inner % 8, dt = inner / 8;
  const int q0 = qt * 256, d0 = dt * 256;

  f32x4 acc[8][4] = {};
  gemm256<N_ / 64>(P + ((long)b * N_ + q0) * N_, N_,
                   VsT + ((long)b * D_ + d0) * N_, N_, acc);

  const int l = threadIdx.x & 63, w = threadIdx.x >> 6;
  const int lr = l & 15, orow = (l >> 4) * 4;
  const int wm = w >> 2, wn = w & 3;
  #pragma unroll
  for (int mf = 0; mf < 8; ++mf)
    #pragma unroll
    for (int nf = 0; nf < 4; ++nf) {
      int dd = d0 + wn * 64 + nf * 16 + lr;
      #pragma unroll
      for (int r = 0; r < 4; ++r) {
        int q = q0 + wm * 128 + mf * 16 + orow + r;
        long idx = ((long)b * N_ + q) * D_ + dd;
        out[idx] = acc[mf][nf][r] + bf2f(xb[idx]);
      }
    }
}

extern "C" void kernel_launch(void* const* d_in, const int* in_sizes, int n_in,
                              void* d_out, int out_size, void* d_ws, size_t ws_size,
                              hipStream_t stream) {
  const float* x  = (const float*)d_in[0];
  const float* Wq = (const float*)d_in[1];
  const float* bq = (const float*)d_in[2];
  const float* Wk = (const float*)d_in[3];
  const float* bk = (const float*)d_in[4];
  const float* Wv = (const float*)d_in[5];
  const float* bv = (const float*)d_in[6];

  char* ws = (char*)d_ws;
  u16* xb  = (u16*)(ws + 0);                          // 25165824 B (live to pv)
  u16* wqb = (u16*)(ws + 25165824);
  u16* wkb = (u16*)(ws + 26345472);
  u16* wvb = (u16*)(ws + 27525120);
  u16* Qs  = (u16*)(ws + 28704768);
  u16* Kb  = (u16*)(ws + 53870592);
  u16* Vb  = (u16*)(ws + 79036416);
  u16* VsT = (u16*)(ws + 104202240);
  u16* P   = (u16*)(ws + 129368064);                  // 67108864 B
  float* denpart = (float*)(ws + 196476928);          // 1048576 B
  (void)in_sizes; (void)n_in; (void)out_size; (void)ws_size;

  cast_kernel<<<7008, 256, 0, stream>>>(x, Wq, Wk, Wv, xb, wqb, wkb, wvb);
  qkv_gemm<<<576, 512, 0, stream>>>(xb, wqb, wkb, wvb, bq, bk, bv, Qs, Kb, Vb);
  qk_exp<<<512, 512, 0, stream>>>(Qs, Kb, P, denpart);
  scale_transpose<<<dim3(12, 32, 8), 256, 0, stream>>>(Vb, denpart, VsT);
  pv_gemm<<<192, 512, 0, stream>>>(P, VsT, xb, (float*)d_out);
}

// Round 9
// 221.026 us; speedup vs baseline: 1.2485x; 1.2485x over previous
//
#include <hip/hip_runtime.h>
#include <stdint.h>

#define B_ 8
#define N_ 2048
#define D_ 768

typedef unsigned short u16;
typedef unsigned int u32;
typedef __attribute__((ext_vector_type(8))) short bf16x8;
typedef __attribute__((ext_vector_type(8))) unsigned short u16x8;
typedef __attribute__((ext_vector_type(4))) float f32x4;

static constexpr float INV_SCALE = 0.10825317547305482f; // 3/sqrt(768)

__device__ __forceinline__ u16 f2bf(float f) {
  union { float f; unsigned u; } v; v.f = f;
  return (u16)((v.u + 0x7FFFu + ((v.u >> 16) & 1u)) >> 16);
}
__device__ __forceinline__ float bf2f(u16 h) {
  union { unsigned u; float f; } v; v.u = ((unsigned)h) << 16;
  return v.f;
}
__device__ __forceinline__ f32x4 mfma16(bf16x8 a, bf16x8 b, f32x4 c) {
  return __builtin_amdgcn_mfma_f32_16x16x32_bf16(a, b, c, 0, 0, 0);
}
__device__ __forceinline__ void gl_lds16(const u16* g, u16* l) {
  __builtin_amdgcn_global_load_lds(
      (const __attribute__((address_space(1))) u32*)g,
      (__attribute__((address_space(3))) u32*)l, 16, 0, 0);
}

// ---------------- K0: cast x, Wq, Wk, Wv to bf16 ----------------
__global__ __launch_bounds__(256) void cast_kernel(
    const float* __restrict__ x, const float* __restrict__ wq,
    const float* __restrict__ wk, const float* __restrict__ wv,
    u16* __restrict__ xb, u16* __restrict__ wqb,
    u16* __restrict__ wkb, u16* __restrict__ wvb) {
  const long NX = (long)B_ * N_ * D_;
  const long NW = (long)D_ * D_;
  long i = ((long)blockIdx.x * 256 + threadIdx.x) * 8;
  const float* src; u16* dst; long off;
  if (i < NX) { src = x; dst = xb; off = i; }
  else {
    long j = i - NX;
    int seg = (int)(j / NW);
    off = j - (long)seg * NW;
    src = seg == 0 ? wq : (seg == 1 ? wk : wv);
    dst = seg == 0 ? wqb : (seg == 1 ? wkb : wvb);
  }
  float4 a = *(const float4*)(src + off);
  float4 b = *(const float4*)(src + off + 4);
  u16x8 o;
  o[0]=f2bf(a.x); o[1]=f2bf(a.y); o[2]=f2bf(a.z); o[3]=f2bf(a.w);
  o[4]=f2bf(b.x); o[5]=f2bf(b.y); o[6]=f2bf(b.z); o[7]=f2bf(b.w);
  *(u16x8*)(dst + off) = o;
}

// ==== 256x256 BK=64 GEMM core: 8 waves (2M x 4N), wave tile 128x64 ====
// Per K-tile: 2 half-phases with REGISTER REUSE (24 ds_read_b128 / 64 MFMA
// per wave — m201's ratio):
//   ph0: stage A(t+1) [4 gl_lds]; vmcnt(4) => tile t's 8 loads landed
//        (the 4 just issued stay in flight); barrier; read bf[4][2]+af0[4][2]
//        (16 reads); 32 MFMA (rows 0-63 of wave tile).
//   ph1: stage B(t+1) [4 gl_lds, no wait]; read af1 (8 reads; bf reused in
//        regs); 32 MFMA (rows 64-127); barrier (tile end).
// 2 barriers/K-tile; counted vmcnt never 0 mid-loop.
// WAR-safe: buffer X read only during tile t; overwritten by stages of tile
// t+1, which all occur after tile t's end barrier.
// Swizzle both sides (rule 21, verified R8: conflicts 0, correct output):
// phys 16B-slot = logical ^ (row&7); writer pre-swizzles global source slot.
template<int NT>
__device__ __forceinline__ void gemm256(
    const u16* __restrict__ Ag, long lda,
    const u16* __restrict__ Bg, long ldb,
    f32x4 (&acc)[8][4]) {
  __shared__ u16 Ab[2][16384];
  __shared__ u16 Bb[2][16384];
  const int t_ = threadIdx.x, l = t_ & 63, w = t_ >> 6;
  const int lr = l & 15, kq = l >> 4;          // kq in [0,4)
  const int wm = w >> 2, wn = w & 3;
  const int arow = wm * 128, brow = wn * 64;

  // staging: lane writes LDS byte j*8192 + w*1024 + l*16
  //   -> row = j*64 + w*8 + (l>>3), phys slot = l&7
  //   source logical slot = (l&7) ^ (l>>3)  (= phys ^ (row&7))
  const int s_rowl = l >> 3;
  const int s_sl = (l & 7) ^ (l >> 3);
  auto STAGE_A = [&](u16* As, int kt) {
    #pragma unroll
    for (int j = 0; j < 4; ++j) {
      const int row = j * 64 + w * 8 + s_rowl;
      gl_lds16(Ag + (long)row * lda + kt * 64 + s_sl * 8,
               As + ((j * 8192 + w * 1024) >> 1));
    }
  };
  auto STAGE_B = [&](u16* Bs, int kt) {
    #pragma unroll
    for (int j = 0; j < 4; ++j) {
      const int row = j * 64 + w * 8 + s_rowl;
      gl_lds16(Bg + (long)row * ldb + kt * 64 + s_sl * 8,
               Bs + ((j * 8192 + w * 1024) >> 1));
    }
  };

#define TILE(XA, XB, YA, YB, kt, DOST)                                       \
  {                                                                          \
    if (DOST) {                                                              \
      STAGE_A(YA, (kt) + 1);                                                 \
      asm volatile("s_waitcnt vmcnt(4)" ::: "memory");                       \
    } else {                                                                 \
      asm volatile("s_waitcnt vmcnt(0)" ::: "memory");                       \
    }                                                                        \
    __builtin_amdgcn_s_barrier();                                            \
    asm volatile("" ::: "memory");                                           \
    bf16x8 bf[4][2];                                                         \
    _Pragma("unroll")                                                        \
    for (int nf = 0; nf < 4; ++nf) {                                         \
      const int row = brow + nf * 16 + lr;                                   \
      _Pragma("unroll")                                                      \
      for (int ks = 0; ks < 2; ++ks)                                         \
        bf[nf][ks] = *(const bf16x8*)(XB + row * 64 +                        \
                        (((4 * ks + kq) ^ (lr & 7)) * 8));                   \
    }                                                                        \
    {                                                                        \
      bf16x8 af[4][2];                                                       \
      _Pragma("unroll")                                                      \
      for (int mf = 0; mf < 4; ++mf) {                                       \
        const int row = arow + mf * 16 + lr;                                 \
        _Pragma("unroll")                                                    \
        for (int ks = 0; ks < 2; ++ks)                                       \
          af[mf][ks] = *(const bf16x8*)(XA + row * 64 +                      \
                          (((4 * ks + kq) ^ (lr & 7)) * 8));                 \
      }                                                                      \
      __builtin_amdgcn_s_setprio(1);                                         \
      _Pragma("unroll")                                                      \
      for (int ks = 0; ks < 2; ++ks)                                         \
        _Pragma("unroll")                                                    \
        for (int mf = 0; mf < 4; ++mf)                                       \
          _Pragma("unroll")                                                  \
          for (int nf = 0; nf < 4; ++nf)                                     \
            acc[mf][nf] = mfma16(af[mf][ks], bf[nf][ks], acc[mf][nf]);       \
      __builtin_amdgcn_s_setprio(0);                                         \
    }                                                                        \
    if (DOST) STAGE_B(YB, (kt) + 1);                                         \
    {                                                                        \
      bf16x8 af[4][2];                                                       \
      _Pragma("unroll")                                                      \
      for (int mf = 0; mf < 4; ++mf) {                                       \
        const int row = arow + 64 + mf * 16 + lr;                            \
        _Pragma("unroll")                                                    \
        for (int ks = 0; ks < 2; ++ks)                                       \
          af[mf][ks] = *(const bf16x8*)(XA + row * 64 +                      \
                          (((4 * ks + kq) ^ (lr & 7)) * 8));                 \
      }                                                                      \
      __builtin_amdgcn_s_setprio(1);                                         \
      _Pragma("unroll")                                                      \
      for (int ks = 0; ks < 2; ++ks)                                         \
        _Pragma("unroll")                                                    \
        for (int mf = 0; mf < 4; ++mf)                                       \
          _Pragma("unroll")                                                  \
          for (int nf = 0; nf < 4; ++nf)                                     \
            acc[4 + mf][nf] = mfma16(af[mf][ks], bf[nf][ks], acc[4 + mf][nf]); \
      __builtin_amdgcn_s_setprio(0);                                         \
    }                                                                        \
    asm volatile("" ::: "memory");                                           \
    __builtin_amdgcn_s_barrier();                                            \
  }

  STAGE_A(Ab[0], 0);
  STAGE_B(Bb[0], 0);
  for (int t2 = 0; t2 < NT; t2 += 2) {
    TILE(Ab[0], Bb[0], Ab[1], Bb[1], t2, true)
    TILE(Ab[1], Bb[1], Ab[0], Bb[0], t2 + 1, (t2 + 2 < NT))
  }
#undef TILE
}

// ---------------- K1: Q/K/V = x @ W^T + b (Q scaled) ----------------
// grid 576 = 64 rt x 3 ct x 3 mat; XCD = rt-band (8 rt x 256 rows = 3 MB).
__global__ __launch_bounds__(512, 2) void qkv_gemm(
    const u16* __restrict__ xb,
    const u16* __restrict__ wq, const u16* __restrict__ wk, const u16* __restrict__ wv,
    const float* __restrict__ bq, const float* __restrict__ bk, const float* __restrict__ bv,
    u16* __restrict__ Qs, u16* __restrict__ Kb, u16* __restrict__ Vb) {
  const int lin = blockIdx.x;
  const int xcd = lin & 7, inner = lin >> 3;          // inner: 0..71
  const int rt = xcd * 8 + (inner & 7);
  const int rest = inner >> 3;                        // 0..8
  const int ct = rest % 3, mat = rest / 3;
  const u16* W = mat == 0 ? wq : (mat == 1 ? wk : wv);
  const float* bias = mat == 0 ? bq : (mat == 1 ? bk : bv);
  u16* out = mat == 0 ? Qs : (mat == 1 ? Kb : Vb);
  const float scl = mat == 0 ? INV_SCALE : 1.0f;
  const int rbase = rt * 256, cbase = ct * 256;

  f32x4 acc[8][4] = {};
  gemm256<D_ / 64>(xb + (long)rbase * D_, D_, W + (long)cbase * D_, D_, acc);

  const int l = threadIdx.x & 63, w = threadIdx.x >> 6;
  const int lr = l & 15, orow = (l >> 4) * 4;
  const int wm = w >> 2, wn = w & 3;
  #pragma unroll
  for (int mf = 0; mf < 8; ++mf)
    #pragma unroll
    for (int nf = 0; nf < 4; ++nf) {
      int col = cbase + wn * 64 + nf * 16 + lr;
      float bc = bias[col];
      #pragma unroll
      for (int r = 0; r < 4; ++r) {
        int row = rbase + wm * 128 + mf * 16 + orow + r;
        out[(long)row * D_ + col] = f2bf((acc[mf][nf][r] + bc) * scl);
      }
    }
}

// ---------------- K2: P = exp(Q.K^T), den partials ----------------
// grid 512 = 8 kblk x 8 qblk x 8 b; XCD = one b.
__global__ __launch_bounds__(512, 2) void qk_exp(
    const u16* __restrict__ Qs, const u16* __restrict__ Kb,
    u16* __restrict__ P, float* __restrict__ denpart) {
  const int lin = blockIdx.x;
  const int b = lin & 7, inner = lin >> 3;            // inner: 0..63
  const int kblk = inner & 7, qblk = inner >> 3;

  f32x4 acc[8][4] = {};
  gemm256<D_ / 64>(Qs + ((long)b * N_ + qblk * 256) * D_, D_,
                   Kb + ((long)b * N_ + kblk * 256) * D_, D_, acc);

  const int tt = threadIdx.x, l = tt & 63, w = tt >> 6;
  const int lr = l & 15, orow = (l >> 4) * 4;
  const int wm = w >> 2, wn = w & 3;
  float csum[4] = {0.f, 0.f, 0.f, 0.f};
  #pragma unroll
  for (int mf = 0; mf < 8; ++mf)
    #pragma unroll
    for (int nf = 0; nf < 4; ++nf) {
      long kk = kblk * 256 + wn * 64 + nf * 16 + lr;
      #pragma unroll
      for (int r = 0; r < 4; ++r) {
        long q = qblk * 256 + wm * 128 + mf * 16 + orow + r;
        float e = __expf(acc[mf][nf][r]);
        u16 pe = f2bf(e);
        P[((long)b * N_ + q) * N_ + kk] = pe;
        csum[nf] += bf2f(pe);
      }
    }
  // reduce over orow lane-groups -> column sums for this wave's 128 q rows
  #pragma unroll
  for (int nf = 0; nf < 4; ++nf) {
    csum[nf] += __shfl_xor(csum[nf], 16);
    csum[nf] += __shfl_xor(csum[nf], 32);
  }
  if (l < 16) {
    #pragma unroll
    for (int nf = 0; nf < 4; ++nf)
      denpart[((long)(qblk * 2 + wm) * B_ + b) * N_ +
              kblk * 256 + wn * 64 + nf * 16 + l] = csum[nf];
  }
}

// ---------------- K3: VsT[b][d][k] = V[b][k][d] / den[b][k] ----------------
__global__ __launch_bounds__(256) void scale_transpose(
    const u16* __restrict__ Vb, const float* __restrict__ denpart,
    u16* __restrict__ VsT) {
  const int b = blockIdx.z, k0 = blockIdx.y * 64, d0 = blockIdx.x * 64;
  __shared__ float tile[64][65];
  __shared__ float invden[64];
  const int t = threadIdx.x;
  if (t < 64) {
    float s = 0.f;
    for (int qs = 0; qs < 16; ++qs)
      s += denpart[((long)qs * B_ + b) * N_ + k0 + t];
    invden[t] = 1.0f / s;
  }
  __syncthreads();
  for (int idx = t; idx < 4096; idx += 256) {
    int kl = idx >> 6, dl = idx & 63;
    float v = bf2f(Vb[((long)b * N_ + k0 + kl) * D_ + d0 + dl]) * invden[kl];
    tile[dl][kl] = v;
  }
  __syncthreads();
  for (int idx = t; idx < 4096; idx += 256) {
    int dl = idx >> 6, kl = idx & 63;
    VsT[((long)b * D_ + d0 + dl) * N_ + k0 + kl] = f2bf(tile[dl][kl]);
  }
}

// ---------------- K4: out = P @ Vs + xb (bf16 residual) ----------------
// grid 192 = 8 qt x 3 dt x 8 b; XCD = one b (24 blocks): VsT_b L2-hot.
__global__ __launch_bounds__(512, 2) void pv_gemm(
    const u16* __restrict__ P, const u16* __restrict__ VsT,
    const u16* __restrict__ xb, float* __restrict__ out) {
  const int lin = blockIdx.x;
  const int b = lin & 7, inner = lin >> 3;            // inner: 0..23
  const int qt = inner % 8, dt = inner / 8;
  const int q0 = qt * 256, d0 = dt * 256;

  f32x4 acc[8][4] = {};
  gemm256<N_ / 64>(P + ((long)b * N_ + q0) * N_, N_,
                   VsT + ((long)b * D_ + d0) * N_, N_, acc);

  const int l = threadIdx.x & 63, w = threadIdx.x >> 6;
  const int lr = l & 15, orow = (l >> 4) * 4;
  const int wm = w >> 2, wn = w & 3;
  #pragma unroll
  for (int mf = 0; mf < 8; ++mf)
    #pragma unroll
    for (int nf = 0; nf < 4; ++nf) {
      int dd = d0 + wn * 64 + nf * 16 + lr;
      #pragma unroll
      for (int r = 0; r < 4; ++r) {
        int q = q0 + wm * 128 + mf * 16 + orow + r;
        long idx = ((long)b * N_ + q) * D_ + dd;
        out[idx] = acc[mf][nf][r] + bf2f(xb[idx]);
      }
    }
}

extern "C" void kernel_launch(void* const* d_in, const int* in_sizes, int n_in,
                              void* d_out, int out_size, void* d_ws, size_t ws_size,
                              hipStream_t stream) {
  const float* x  = (const float*)d_in[0];
  const float* Wq = (const float*)d_in[1];
  const float* bq = (const float*)d_in[2];
  const float* Wk = (const float*)d_in[3];
  const float* bk = (const float*)d_in[4];
  const float* Wv = (const float*)d_in[5];
  const float* bv = (const float*)d_in[6];

  char* ws = (char*)d_ws;
  u16* xb  = (u16*)(ws + 0);                          // 25165824 B (live to pv)
  u16* wqb = (u16*)(ws + 25165824);
  u16* wkb = (u16*)(ws + 26345472);
  u16* wvb = (u16*)(ws + 27525120);
  u16* Qs  = (u16*)(ws + 28704768);
  u16* Kb  = (u16*)(ws + 53870592);
  u16* Vb  = (u16*)(ws + 79036416);
  u16* VsT = (u16*)(ws + 104202240);
  u16* P   = (u16*)(ws + 129368064);                  // 67108864 B
  float* denpart = (float*)(ws + 196476928);          // 1048576 B
  (void)in_sizes; (void)n_in; (void)out_size; (void)ws_size;

  cast_kernel<<<7008, 256, 0, stream>>>(x, Wq, Wk, Wv, xb, wqb, wkb, wvb);
  qkv_gemm<<<576, 512, 0, stream>>>(xb, wqb, wkb, wvb, bq, bk, bv, Qs, Kb, Vb);
  qk_exp<<<512, 512, 0, stream>>>(Qs, Kb, P, denpart);
  scale_transpose<<<dim3(12, 32, 8), 256, 0, stream>>>(Vb, denpart, VsT);
  pv_gemm<<<192, 512, 0, stream>>>(P, VsT, xb, (float*)d_out);
}